// Round 4
// baseline (287.740 us; speedup 1.0000x reference)
//
#include <hip/hip_runtime.h>
#include <cstdint>

#define BB 8192
#define TT 50
#define FF 24
#define ROWS 16

typedef __attribute__((ext_vector_type(8))) short short8;
typedef __attribute__((ext_vector_type(4))) float f32x4;

__device__ __forceinline__ float sigf(float x){ return 1.0f/(1.0f + __expf(-x)); }

// 2-way bf16 split (truncation): w ~= s1 + s2 to ~16 mantissa bits
__device__ __forceinline__ void split2(float w, unsigned short& s1, unsigned short& s2){
  unsigned b = __float_as_uint(w);
  s1 = (unsigned short)(b >> 16);
  float r = w - __uint_as_float(b & 0xFFFF0000u);
  s2 = (unsigned short)(__float_as_uint(r) >> 16);
}

#define MFMA(A,B,C) __builtin_amdgcn_mfma_f32_16x16x32_bf16((A),(B),(C),0,0,0)

// Round 12: round-11 structure with the 16-wave barrier group split in two.
// ROWS 32->16, grid 256->512 (2 blocks/CU), 8 waves/block. Per-wave work,
// MFMA count, LDS strides, numerics: byte-identical to round 11 (the rg
// dimension became the block index). Rationale: rounds 2-3 showed no pipe
// >55% busy and phase time ~2x the busiest pipe -- a barrier-bubble
// skeleton. Two independent barrier groups per CU let one group's waves
// issue while the other sits in its barrier drain / dependency-chain tail.
// zcol map per 16-wide tile tl: zc = (li&3)*<4H/4> + 4*tl + (li>>2), so
// lane (quad,li) reg i2 = gate i2 of hidden 4*tl+quad for batch row li.

// ---------------- ae_A: L1 + L2 -> h2ws[B][32] ----------------
__global__ __launch_bounds__(512,4) void ae_A(
    const float* __restrict__ x,
    const float* __restrict__ W1, const float* __restrict__ U1, const float* __restrict__ b1,
    const float* __restrict__ W2, const float* __restrict__ U2, const float* __restrict__ b2,
    float* __restrict__ h2ws)
{
  constexpr int AS1 = 104, AS2 = 40;
  __shared__ __align__(16) unsigned short a1[2][2][ROWS*AS1]; // [slot][split][row*AS1 + (x24|h1 64|pad)]
  __shared__ __align__(16) unsigned short a2[2][2][ROWS*AS2]; // [slot][split][row*AS2 + h2(32)|pad]

  const int tid = threadIdx.x, wave = tid>>6, lane = tid&63;
  const int quad = lane>>4, li = lane&15;
  const int b0 = blockIdx.x*ROWS;
  const int arow = li;                   // batch row this wave touches

  // L1 weight A-frags: tiles tl = 2*wave+tp (16 tiles cover 256 zcols)
  short8 A1w[2][3], A2w[2][3];
  f32x4 bi1[2];
#pragma unroll
  for (int tp=0; tp<2; ++tp){
    const int tl = 2*wave + tp;
    const int zc = (li&3)*64 + 4*tl + (li>>2);
#pragma unroll
    for (int ks=0; ks<3; ++ks){
      short8 v1, v2;
#pragma unroll
      for (int j=0; j<8; ++j){
        const int k = ks*32 + quad*8 + j;
        float w = (k<24) ? W1[k*256+zc] : ((k<88) ? U1[(k-24)*256+zc] : 0.f);
        unsigned short s1,s2; split2(w,s1,s2);
        v1[j]=(short)s1; v2[j]=(short)s2;
      }
      A1w[tp][ks]=v1; A2w[tp][ks]=v2;
    }
#pragma unroll
    for (int i2=0;i2<4;++i2) bi1[tp][i2] = b1[i2*64 + 4*tl + quad];
  }
  // L2 weight A-frags: tile = wave; 8 tiles cover 128 zcols
  short8 A1w2[3], A2w2[3];
  f32x4 bi2;
  {
    const int zc = (li&3)*32 + 4*wave + (li>>2);
#pragma unroll
    for (int ks=0; ks<3; ++ks){
      short8 v1, v2;
#pragma unroll
      for (int j=0; j<8; ++j){
        const int k = ks*32 + quad*8 + j;
        float w = (k<64) ? W2[k*128+zc] : U2[(k-64)*128+zc];
        unsigned short s1,s2; split2(w,s1,s2);
        v1[j]=(short)s1; v2[j]=(short)s2;
      }
      A1w2[ks]=v1; A2w2[ks]=v2;
    }
#pragma unroll
    for (int i2=0;i2<4;++i2) bi2[i2] = b2[i2*32 + 4*wave + quad];
  }

  // zero LDS (h regions must read 0 at t=0; pads must stay 0 forever)
  { unsigned* p1 = (unsigned*)a1; for (int i=tid;i<2*2*ROWS*AS1/2;i+=512) p1[i]=0u;
    unsigned* p2 = (unsigned*)a2; for (int i=tid;i<2*2*ROWS*AS2/2;i+=512) p2[i]=0u; }
  __syncthreads();
  // stage x(0) into slot 0
  if (tid < ROWS*FF){
    const int r = tid/FF, f = tid - r*FF;
    unsigned short s1,s2; split2(x[((size_t)(b0+r)*TT + 0)*FF + f], s1,s2);
    a1[0][0][r*AS1+f]=s1; a1[0][1][r*AS1+f]=s2;
  }
  // x prefetch (threads tid<384): depth-2 register pipeline
  int pr=0, pf=0; const float* xp=nullptr;
  float va=0.f, vb=0.f;
  const bool st = (tid < ROWS*FF);
  if (st){
    pr = tid/FF; pf = tid - pr*FF;
    xp = x + (size_t)(b0+pr)*TT*FF + pf;
    va = xp[1*FF];   // x(1)
    vb = xp[2*FF];   // x(2)
  }
  float c1s[2] = {0.f,0.f};
  float c2s = 0.f;
  const int rb1 = arow*AS1;
  const int rb2 = arow*AS2;
  const int hw1 = rb1 + 24 + 8*wave + quad;   // +4*tp for tile tp
  const int hw2 = rb2 + 4*wave + quad;
  __syncthreads();

#pragma unroll 1
  for (int t=0; t<=TT; ++t){
    const int s = t&1, ns = s^1;
    // ---- L1: z1(t) + gates -> h1(t) (all waves; B-frag read once) ----
    if (t < TT){
      short8 Ba[3], Bb[3];
#pragma unroll
      for (int ks=0; ks<3; ++ks){
        const int ab = rb1 + ks*32 + quad*8;
        Ba[ks] = *(const short8*)&a1[s][0][ab];
        Bb[ks] = *(const short8*)&a1[s][1][ab];
      }
#pragma unroll
      for (int tp=0; tp<2; ++tp){
        f32x4 C = bi1[tp];
#pragma unroll
        for (int ks=0; ks<3; ++ks){
          C = MFMA(A1w[tp][ks], Ba[ks], C);   // w_hi * a_hi
          C = MFMA(A1w[tp][ks], Bb[ks], C);   // w_hi * a_lo
          C = MFMA(A2w[tp][ks], Ba[ks], C);   // w_lo * a_hi
        }
        const float ig = sigf(C[0]), fg = sigf(C[1]);
        const float gg = fmaxf(C[2],0.f), og = sigf(C[3]);
        const float cn = fg*c1s[tp] + ig*gg; c1s[tp] = cn;
        const float h = og*fmaxf(cn,0.f);
        unsigned short s1,s2; split2(h,s1,s2);
        a1[ns][0][hw1+4*tp] = s1; a1[ns][1][hw1+4*tp] = s2;
      }
    }
    // ---- L2: z2(t-1) + gates -> h2(t-1) (1 tile/wave) ----
    if (t >= 1){
      f32x4 C = bi2;
#pragma unroll
      for (int ks=0; ks<2; ++ks){
        const int ab = rb1 + 24 + ks*32 + quad*8;
        short8 Ba = *(const short8*)&a1[s][0][ab];
        short8 Bb = *(const short8*)&a1[s][1][ab];
        C = MFMA(A1w2[ks], Ba, C);
        C = MFMA(A1w2[ks], Bb, C);
        C = MFMA(A2w2[ks], Ba, C);
      }
      {
        const int ab = rb2 + quad*8;
        short8 Ba = *(const short8*)&a2[s][0][ab];
        short8 Bb = *(const short8*)&a2[s][1][ab];
        C = MFMA(A1w2[2], Ba, C);
        C = MFMA(A1w2[2], Bb, C);
        C = MFMA(A2w2[2], Ba, C);
      }
      const float ig = sigf(C[0]), fg = sigf(C[1]);
      const float gg = fmaxf(C[2],0.f), og = sigf(C[3]);
      const float cn = fg*c2s + ig*gg; c2s = cn;
      const float h = og*fmaxf(cn,0.f);
      if (t < TT){
        unsigned short s1,s2; split2(h,s1,s2);
        a2[ns][0][hw2] = s1; a2[ns][1][hw2] = s2;
      } else {
        h2ws[(size_t)(b0+arow)*32 + 4*wave + quad] = h;   // final h2(TT-1)
      }
    }
    // ---- x staging: write x(t+1), prefetch x(t+3) ----
    if (st && t < TT-1){
      unsigned short s1,s2;
      split2(va,s1,s2); a1[ns][0][pr*AS1+pf]=s1; a1[ns][1][pr*AS1+pf]=s2;
      va = vb;
      if (t+3 < TT) vb = xp[(t+3)*FF];
    }
    __syncthreads();
  }
}

// ---------------- ae_C: L3 + fused dense -> out[B][T][24] ----------------
__global__ __launch_bounds__(512,4) void ae_C(
    const float* __restrict__ h2ws,
    const float* __restrict__ W3, const float* __restrict__ U3, const float* __restrict__ b3,
    const float* __restrict__ Wd, const float* __restrict__ bd,
    float* __restrict__ out)
{
  constexpr int AS3 = 72, A2H = 40;
  __shared__ __align__(16) unsigned short a3[2][2][ROWS*AS3];  // [slot][split][row*AS3 + h3(64)|pad]
  __shared__ __align__(16) unsigned short a2h[2][ROWS*A2H];    // h2 splits (static)

  const int tid = threadIdx.x, wave = tid>>6, lane = tid&63;
  const int quad = lane>>4, li = lane&15;
  const int b0 = blockIdx.x*ROWS;
  const int arow = li;

  // U3 A-frags: tiles tl = 2*wave+tp
  short8 A1u[2][2], A2u[2][2];
  short8 A1w3[2], A2w3[2];
  f32x4 bi3[2];
#pragma unroll
  for (int tp=0; tp<2; ++tp){
    const int tl = 2*wave + tp;
    const int zc = (li&3)*64 + 4*tl + (li>>2);
#pragma unroll
    for (int ks=0; ks<2; ++ks){
      short8 v1, v2;
#pragma unroll
      for (int j=0; j<8; ++j){
        const int k = ks*32 + quad*8 + j;
        float w = U3[k*256+zc];
        unsigned short s1,s2; split2(w,s1,s2);
        v1[j]=(short)s1; v2[j]=(short)s2;
      }
      A1u[tp][ks]=v1; A2u[tp][ks]=v2;
    }
    { // W3 (K=32, prologue only)
      short8 v1, v2;
#pragma unroll
      for (int j=0; j<8; ++j){
        const int k = quad*8 + j;
        float w = W3[k*256+zc];
        unsigned short s1,s2; split2(w,s1,s2);
        v1[j]=(short)s1; v2[j]=(short)s2;
      }
      A1w3[tp]=v1; A2w3[tp]=v2;
    }
#pragma unroll
    for (int i2=0;i2<4;++i2) bi3[tp][i2] = b3[i2*64 + 4*tl + quad];
  }

  // dense B-frags: waves 0,1
  const bool dW = (wave < 2);
  const int dcol = wave*16 + li;
  const bool dOK = dW && (dcol < 24);
  const float bdv = dOK ? bd[dcol] : 0.f;
  short8 Bd1[2], Bd2[2];
  if (dW){
#pragma unroll
    for (int ks=0; ks<2; ++ks){
      short8 v1, v2;
#pragma unroll
      for (int j=0; j<8; ++j){
        const int k = ks*32 + quad*8 + j;
        float w = dOK ? Wd[k*24+dcol] : 0.f;
        unsigned short s1,s2; split2(w,s1,s2);
        v1[j]=(short)s1; v2[j]=(short)s2;
      }
      Bd1[ks]=v1; Bd2[ks]=v2;
    }
  }

  // zero a3 (both slots: h3(-1)=0 and pads), stage h2 splits
  { unsigned* p = (unsigned*)a3; for (int i=tid;i<2*2*ROWS*AS3/2;i+=512) p[i]=0u; }
  {
    const int r = tid>>5, ch = tid&31;
    unsigned short s1,s2; split2(h2ws[(size_t)(b0+r)*32 + ch], s1,s2);
    a2h[0][r*A2H+ch]=s1; a2h[1][r*A2H+ch]=s2;
  }
  __syncthreads();

  // ZR = b3 + h2@W3 (per-lane, C-init for every phase)
  f32x4 zr[2];
  {
    const int ab = arow*A2H + quad*8;
    short8 Ba = *(const short8*)&a2h[0][ab];
    short8 Bb = *(const short8*)&a2h[1][ab];
#pragma unroll
    for (int tp=0; tp<2; ++tp){
      f32x4 C = bi3[tp];
      C = MFMA(A1w3[tp], Ba, C);
      C = MFMA(A1w3[tp], Bb, C);
      C = MFMA(A2w3[tp], Ba, C);
      zr[tp] = C;
    }
  }
  float c3s[2] = {0.f,0.f};
  const int rb3 = arow*AS3;
  const int hw3 = rb3 + 8*wave + quad;       // +4*tp

#pragma unroll 1
  for (int t=0; t<=TT; ++t){
    const int s = t&1, ns = s^1;
    if (t < TT){
      short8 Ba[2], Bb[2];
#pragma unroll
      for (int ks=0; ks<2; ++ks){
        const int ab = rb3 + ks*32 + quad*8;
        Ba[ks] = *(const short8*)&a3[s][0][ab];
        Bb[ks] = *(const short8*)&a3[s][1][ab];
      }
#pragma unroll
      for (int tp=0; tp<2; ++tp){
        f32x4 C = zr[tp];
#pragma unroll
        for (int ks=0; ks<2; ++ks){
          C = MFMA(A1u[tp][ks], Ba[ks], C);
          C = MFMA(A1u[tp][ks], Bb[ks], C);
          C = MFMA(A2u[tp][ks], Ba[ks], C);
        }
        const float ig = sigf(C[0]), fg = sigf(C[1]);
        const float gg = fmaxf(C[2],0.f), og = sigf(C[3]);
        const float cn = fg*c3s[tp] + ig*gg; c3s[tp] = cn;
        const float h = og*fmaxf(cn,0.f);
        unsigned short s1,s2; split2(h,s1,s2);
        a3[ns][0][hw3+4*tp]=s1; a3[ns][1][hw3+4*tp]=s2;
      }
      // dense on h3(t-1) (same B-frags), out column t-1
      if (dW && t > 0){
        f32x4 Cd = {bdv,bdv,bdv,bdv};
#pragma unroll
        for (int ks=0; ks<2; ++ks){
          Cd = MFMA(Ba[ks], Bd1[ks], Cd);   // a_hi * w_hi (normal orientation)
          Cd = MFMA(Ba[ks], Bd2[ks], Cd);   // a_hi * w_lo
          Cd = MFMA(Bb[ks], Bd1[ks], Cd);   // a_lo * w_hi
        }
        if (dcol < 24){
#pragma unroll
          for (int i2=0;i2<4;++i2)
            out[((size_t)(b0+quad*4+i2)*TT + (t-1))*FF + dcol] = Cd[i2];
        }
      }
    } else {
      // t == TT: final dense on h3(TT-1)
      if (dW){
        f32x4 Cd = {bdv,bdv,bdv,bdv};
#pragma unroll
        for (int ks=0; ks<2; ++ks){
          const int ab = rb3 + ks*32 + quad*8;
          short8 Ba = *(const short8*)&a3[s][0][ab];
          short8 Bb = *(const short8*)&a3[s][1][ab];
          Cd = MFMA(Ba, Bd1[ks], Cd);
          Cd = MFMA(Ba, Bd2[ks], Cd);
          Cd = MFMA(Bb, Bd1[ks], Cd);
        }
        if (dcol < 24){
#pragma unroll
          for (int i2=0;i2<4;++i2)
            out[((size_t)(b0+quad*4+i2)*TT + (TT-1))*FF + dcol] = Cd[i2];
        }
      }
    }
    __syncthreads();
  }
}

extern "C" void kernel_launch(void* const* d_in, const int* in_sizes, int n_in,
                              void* d_out, int out_size, void* d_ws, size_t ws_size,
                              hipStream_t stream){
  const float* x  = (const float*)d_in[0];
  const float* W1 = (const float*)d_in[1];
  const float* U1 = (const float*)d_in[2];
  const float* b1 = (const float*)d_in[3];
  const float* W2 = (const float*)d_in[4];
  const float* U2 = (const float*)d_in[5];
  const float* b2 = (const float*)d_in[6];
  const float* W3 = (const float*)d_in[7];
  const float* U3 = (const float*)d_in[8];
  const float* b3 = (const float*)d_in[9];
  const float* Wd = (const float*)d_in[10];
  const float* bd = (const float*)d_in[11];
  float* out = (float*)d_out;
  float* h2ws = (float*)d_ws;                  // [B][32] = 1 MB

  hipLaunchKernelGGL(ae_A, dim3(BB/ROWS), dim3(512), 0, stream,
                     x, W1, U1, b1, W2, U2, b2, h2ws);
  hipLaunchKernelGGL(ae_C, dim3(BB/ROWS), dim3(512), 0, stream,
                     h2ws, W3, U3, b3, Wd, bd, out);
}

// Round 5
// 259.261 us; speedup vs baseline: 1.1098x; 1.1098x over previous
//
#include <hip/hip_runtime.h>
#include <cstdint>

#define BB 8192
#define TT 50
#define FF 24
#define ROWS 32

typedef __attribute__((ext_vector_type(8))) short short8;
typedef __attribute__((ext_vector_type(4))) float f32x4;

__device__ __forceinline__ float sigf(float x){ return 1.0f/(1.0f + __expf(-x)); }

// 2-way bf16 split (truncation) -- weights only: w ~= s1 + s2 (~16 mantissa bits)
__device__ __forceinline__ void split2(float w, unsigned short& s1, unsigned short& s2){
  unsigned b = __float_as_uint(w);
  s1 = (unsigned short)(b >> 16);
  float r = w - __uint_as_float(b & 0xFFFF0000u);
  s2 = (unsigned short)(__float_as_uint(r) >> 16);
}

// single bf16 with round-to-nearest-even -- activations
__device__ __forceinline__ unsigned short rne16(float v){
  unsigned b = __float_as_uint(v);
  b += 0x7FFFu + ((b >> 16) & 1u);
  return (unsigned short)(b >> 16);
}

#define MFMA(A,B,C) __builtin_amdgcn_mfma_f32_16x16x32_bf16((A),(B),(C),0,0,0)

// Round 13: R3 skeleton (transposed MFMA, 1 barrier/step, ROWS=32, 16 waves,
// 256 blocks) with the 3-product bf16 split cut to 2 products:
//   weights stay 2-split (registers, exact), activations stored as ONE
//   RNE-rounded bf16:  z = w_hi*a + w_lo*a.
// Cuts per phase: MFMA 27->18/wave, LDS b128 reads 12->6, h-writes 6->3,
// split2-of-h (~15 VALU) -> 3-op RNE. LDS footprint -40%. Numerics: weight
// error ~2^-17, activation error ~2^-10 unbiased (RNE) through a
// contractive recurrence -> expected absmax 1e-4..1e-3.
// Also: x-prefetch global load issued at phase TOP so the vmcnt(0) drain
// before s_barrier overlaps the phase compute.
// zcol map per 16-wide tile tl: zc = (li&3)*<4H/4> + 4*tl + (li>>2), so
// lane (quad,li) reg i2 = gate i2 (i,f,g,o) of hidden 4*tl+quad, row li.

// ---------------- ae_A: L1 + L2 -> h2ws[B][32] ----------------
__global__ __launch_bounds__(1024,4) void ae_A(
    const float* __restrict__ x,
    const float* __restrict__ W1, const float* __restrict__ U1, const float* __restrict__ b1,
    const float* __restrict__ W2, const float* __restrict__ U2, const float* __restrict__ b2,
    float* __restrict__ h2ws)
{
  constexpr int AS1 = 104, AS2 = 40;
  __shared__ __align__(16) unsigned short a1[2][ROWS*AS1]; // [slot][row*AS1 + (x24|h1 64|pad)]
  __shared__ __align__(16) unsigned short a2[2][ROWS*AS2]; // [slot][row*AS2 + h2(32)|pad]

  const int tid = threadIdx.x, wave = tid>>6, lane = tid&63;
  const int quad = lane>>4, li = lane&15;
  const int w7 = wave&7, rg = wave>>3;
  const int b0 = blockIdx.x*ROWS;
  const int arow = rg*16 + li;           // batch row this wave touches

  // L1 weight A-frags (2-split): tiles tl = 2*w7+tp (16 tiles over 8 w7 x 2)
  short8 A1w[2][3], A2w[2][3];
  f32x4 bi1[2];
#pragma unroll
  for (int tp=0; tp<2; ++tp){
    const int tl = 2*w7 + tp;
    const int zc = (li&3)*64 + 4*tl + (li>>2);
#pragma unroll
    for (int ks=0; ks<3; ++ks){
      short8 v1, v2;
#pragma unroll
      for (int j=0; j<8; ++j){
        const int k = ks*32 + quad*8 + j;
        float w = (k<24) ? W1[k*256+zc] : ((k<88) ? U1[(k-24)*256+zc] : 0.f);
        unsigned short s1,s2; split2(w,s1,s2);
        v1[j]=(short)s1; v2[j]=(short)s2;
      }
      A1w[tp][ks]=v1; A2w[tp][ks]=v2;
    }
#pragma unroll
    for (int i2=0;i2<4;++i2) bi1[tp][i2] = b1[i2*64 + 4*tl + quad];
  }
  // L2 weight A-frags: instance (rg, tile w7); 16 instances over 16 waves
  short8 A1w2[3], A2w2[3];
  f32x4 bi2;
  {
    const int zc = (li&3)*32 + 4*w7 + (li>>2);
#pragma unroll
    for (int ks=0; ks<3; ++ks){
      short8 v1, v2;
#pragma unroll
      for (int j=0; j<8; ++j){
        const int k = ks*32 + quad*8 + j;
        float w = (k<64) ? W2[k*128+zc] : U2[(k-64)*128+zc];
        unsigned short s1,s2; split2(w,s1,s2);
        v1[j]=(short)s1; v2[j]=(short)s2;
      }
      A1w2[ks]=v1; A2w2[ks]=v2;
    }
#pragma unroll
    for (int i2=0;i2<4;++i2) bi2[i2] = b2[i2*32 + 4*w7 + quad];
  }

  // zero LDS (h regions read 0 at t=0; pads stay 0)
  { unsigned* p1 = (unsigned*)a1; for (int i=tid;i<2*ROWS*AS1/2;i+=1024) p1[i]=0u;
    unsigned* p2 = (unsigned*)a2; for (int i=tid;i<2*ROWS*AS2/2;i+=1024) p2[i]=0u; }
  __syncthreads();
  // stage x(0) into slot 0
  if (tid < ROWS*FF){
    const int r = tid/FF, f = tid - r*FF;
    a1[0][r*AS1+f] = rne16(x[((size_t)(b0+r)*TT + 0)*FF + f]);
  }
  // x prefetch (threads tid<768): register pipeline va=x(t+1), vb=x(t+2)
  int pr=0, pf=0; const float* xp=nullptr;
  float va=0.f, vb=0.f;
  const bool st = (tid < ROWS*FF);
  if (st){
    pr = tid/FF; pf = tid - pr*FF;
    xp = x + (size_t)(b0+pr)*TT*FF + pf;
    va = xp[1*FF];
    vb = xp[2*FF];
  }
  float c1s[2] = {0.f,0.f};
  float c2s = 0.f;
  const int rb1 = arow*AS1;
  const int rb2 = arow*AS2;
  const int hw1 = rb1 + 24 + 8*w7 + quad;   // +4*tp for tile tp
  const int hw2 = rb2 + 4*w7 + quad;
  __syncthreads();

#pragma unroll 1
  for (int t=0; t<=TT; ++t){
    const int s = t&1, ns = s^1;
    // issue next x load FIRST so it completes during compute (vmcnt drain)
    float vc = 0.f;
    if (st && t+3 < TT) vc = xp[(t+3)*FF];
    // ---- L1: z1(t) + gates -> h1(t) (all waves; B-frag read once) ----
    if (t < TT){
      short8 Ba[3];
#pragma unroll
      for (int ks=0; ks<3; ++ks)
        Ba[ks] = *(const short8*)&a1[s][rb1 + ks*32 + quad*8];
#pragma unroll
      for (int tp=0; tp<2; ++tp){
        f32x4 C = bi1[tp];
#pragma unroll
        for (int ks=0; ks<3; ++ks){
          C = MFMA(A1w[tp][ks], Ba[ks], C);   // w_hi * a
          C = MFMA(A2w[tp][ks], Ba[ks], C);   // w_lo * a
        }
        const float ig = sigf(C[0]), fg = sigf(C[1]);
        const float gg = fmaxf(C[2],0.f), og = sigf(C[3]);
        const float cn = fg*c1s[tp] + ig*gg; c1s[tp] = cn;
        const float h = og*fmaxf(cn,0.f);
        a1[ns][hw1+4*tp] = rne16(h);
      }
    }
    // ---- L2: z2(t-1) + gates -> h2(t-1) (1 instance/wave) ----
    if (t >= 1){
      f32x4 C = bi2;
#pragma unroll
      for (int ks=0; ks<2; ++ks){
        short8 Ba = *(const short8*)&a1[s][rb1 + 24 + ks*32 + quad*8];
        C = MFMA(A1w2[ks], Ba, C);
        C = MFMA(A2w2[ks], Ba, C);
      }
      {
        short8 Ba = *(const short8*)&a2[s][rb2 + quad*8];
        C = MFMA(A1w2[2], Ba, C);
        C = MFMA(A2w2[2], Ba, C);
      }
      const float ig = sigf(C[0]), fg = sigf(C[1]);
      const float gg = fmaxf(C[2],0.f), og = sigf(C[3]);
      const float cn = fg*c2s + ig*gg; c2s = cn;
      const float h = og*fmaxf(cn,0.f);
      if (t < TT){
        a2[ns][hw2] = rne16(h);
      } else {
        h2ws[(size_t)(b0+arow)*32 + 4*w7 + quad] = h;   // final h2(TT-1), f32
      }
    }
    // ---- x staging: write x(t+1) ----
    if (st && t < TT-1){
      a1[ns][pr*AS1+pf] = rne16(va);
      va = vb; vb = vc;
    }
    __syncthreads();
  }
}

// ---------------- ae_C: L3 + fused dense -> out[B][T][24] ----------------
__global__ __launch_bounds__(1024,4) void ae_C(
    const float* __restrict__ h2ws,
    const float* __restrict__ W3, const float* __restrict__ U3, const float* __restrict__ b3,
    const float* __restrict__ Wd, const float* __restrict__ bd,
    float* __restrict__ out)
{
  constexpr int AS3 = 72, A2H = 40;
  __shared__ __align__(16) unsigned short a3[2][ROWS*AS3];  // [slot][row*AS3 + h3(64)|pad]
  __shared__ __align__(16) unsigned short a2h[ROWS*A2H];    // h2 bf16 (static)

  const int tid = threadIdx.x, wave = tid>>6, lane = tid&63;
  const int quad = lane>>4, li = lane&15;
  const int w7 = wave&7, rg = wave>>3;
  const int b0 = blockIdx.x*ROWS;
  const int arow = rg*16 + li;

  // U3 A-frags (2-split): tiles tl = 2*w7+tp
  short8 A1u[2][2], A2u[2][2];
  short8 A1w3[2], A2w3[2];
  f32x4 bi3[2];
#pragma unroll
  for (int tp=0; tp<2; ++tp){
    const int tl = 2*w7 + tp;
    const int zc = (li&3)*64 + 4*tl + (li>>2);
#pragma unroll
    for (int ks=0; ks<2; ++ks){
      short8 v1, v2;
#pragma unroll
      for (int j=0; j<8; ++j){
        const int k = ks*32 + quad*8 + j;
        float w = U3[k*256+zc];
        unsigned short s1,s2; split2(w,s1,s2);
        v1[j]=(short)s1; v2[j]=(short)s2;
      }
      A1u[tp][ks]=v1; A2u[tp][ks]=v2;
    }
    { // W3 (K=32, prologue only)
      short8 v1, v2;
#pragma unroll
      for (int j=0; j<8; ++j){
        const int k = quad*8 + j;
        float w = W3[k*256+zc];
        unsigned short s1,s2; split2(w,s1,s2);
        v1[j]=(short)s1; v2[j]=(short)s2;
      }
      A1w3[tp]=v1; A2w3[tp]=v2;
    }
#pragma unroll
    for (int i2=0;i2<4;++i2) bi3[tp][i2] = b3[i2*64 + 4*tl + quad];
  }

  // dense B-frags (2-split weights): waves w7<2 of each rg
  const bool dW = (w7 < 2);
  const int dcol = w7*16 + li;
  const bool dOK = dW && (dcol < 24);
  const float bdv = dOK ? bd[dcol] : 0.f;
  short8 Bd1[2], Bd2[2];
  if (dW){
#pragma unroll
    for (int ks=0; ks<2; ++ks){
      short8 v1, v2;
#pragma unroll
      for (int j=0; j<8; ++j){
        const int k = ks*32 + quad*8 + j;
        float w = dOK ? Wd[k*24+dcol] : 0.f;
        unsigned short s1,s2; split2(w,s1,s2);
        v1[j]=(short)s1; v2[j]=(short)s2;
      }
      Bd1[ks]=v1; Bd2[ks]=v2;
    }
  }

  // zero a3 (both slots), stage h2 (RNE bf16)
  { unsigned* p = (unsigned*)a3; for (int i=tid;i<2*ROWS*AS3/2;i+=1024) p[i]=0u; }
  if (tid < ROWS*32){
    const int r = tid>>5, ch = tid&31;
    a2h[r*A2H+ch] = rne16(h2ws[(size_t)(b0+r)*32 + ch]);
  }
  __syncthreads();

  // ZR = b3 + h2@W3 (per-lane, C-init for every phase)
  f32x4 zr[2];
  {
    short8 Ba = *(const short8*)&a2h[arow*A2H + quad*8];
#pragma unroll
    for (int tp=0; tp<2; ++tp){
      f32x4 C = bi3[tp];
      C = MFMA(A1w3[tp], Ba, C);
      C = MFMA(A2w3[tp], Ba, C);
      zr[tp] = C;
    }
  }
  float c3s[2] = {0.f,0.f};
  const int rb3 = arow*AS3;
  const int hw3 = rb3 + 8*w7 + quad;       // +4*tp

#pragma unroll 1
  for (int t=0; t<=TT; ++t){
    const int s = t&1, ns = s^1;
    if (t < TT){
      short8 Ba[2];
#pragma unroll
      for (int ks=0; ks<2; ++ks)
        Ba[ks] = *(const short8*)&a3[s][rb3 + ks*32 + quad*8];
#pragma unroll
      for (int tp=0; tp<2; ++tp){
        f32x4 C = zr[tp];
#pragma unroll
        for (int ks=0; ks<2; ++ks){
          C = MFMA(A1u[tp][ks], Ba[ks], C);
          C = MFMA(A2u[tp][ks], Ba[ks], C);
        }
        const float ig = sigf(C[0]), fg = sigf(C[1]);
        const float gg = fmaxf(C[2],0.f), og = sigf(C[3]);
        const float cn = fg*c3s[tp] + ig*gg; c3s[tp] = cn;
        const float h = og*fmaxf(cn,0.f);
        a3[ns][hw3+4*tp] = rne16(h);
      }
      // dense on h3(t-1) (same Ba frags), out column t-1
      if (dW && t > 0){
        f32x4 Cd = {bdv,bdv,bdv,bdv};
#pragma unroll
        for (int ks=0; ks<2; ++ks){
          Cd = MFMA(Ba[ks], Bd1[ks], Cd);   // a * w_hi (normal orientation)
          Cd = MFMA(Ba[ks], Bd2[ks], Cd);   // a * w_lo
        }
        if (dcol < 24){
#pragma unroll
          for (int i2=0;i2<4;++i2)
            out[((size_t)(b0+rg*16+quad*4+i2)*TT + (t-1))*FF + dcol] = Cd[i2];
        }
      }
    } else {
      // t == TT: final dense on h3(TT-1)
      if (dW){
        f32x4 Cd = {bdv,bdv,bdv,bdv};
#pragma unroll
        for (int ks=0; ks<2; ++ks){
          short8 Ba = *(const short8*)&a3[s][rb3 + ks*32 + quad*8];
          Cd = MFMA(Ba, Bd1[ks], Cd);
          Cd = MFMA(Ba, Bd2[ks], Cd);
        }
        if (dcol < 24){
#pragma unroll
          for (int i2=0;i2<4;++i2)
            out[((size_t)(b0+rg*16+quad*4+i2)*TT + (TT-1))*FF + dcol] = Cd[i2];
        }
      }
    }
    __syncthreads();
  }
}

extern "C" void kernel_launch(void* const* d_in, const int* in_sizes, int n_in,
                              void* d_out, int out_size, void* d_ws, size_t ws_size,
                              hipStream_t stream){
  const float* x  = (const float*)d_in[0];
  const float* W1 = (const float*)d_in[1];
  const float* U1 = (const float*)d_in[2];
  const float* b1 = (const float*)d_in[3];
  const float* W2 = (const float*)d_in[4];
  const float* U2 = (const float*)d_in[5];
  const float* b2 = (const float*)d_in[6];
  const float* W3 = (const float*)d_in[7];
  const float* U3 = (const float*)d_in[8];
  const float* b3 = (const float*)d_in[9];
  const float* Wd = (const float*)d_in[10];
  const float* bd = (const float*)d_in[11];
  float* out = (float*)d_out;
  float* h2ws = (float*)d_ws;                  // [B][32] = 1 MB

  hipLaunchKernelGGL(ae_A, dim3(BB/ROWS), dim3(1024), 0, stream,
                     x, W1, U1, b1, W2, U2, b2, h2ws);
  hipLaunchKernelGGL(ae_C, dim3(BB/ROWS), dim3(1024), 0, stream,
                     h2ws, W3, U3, b3, Wd, bd, out);
}

// Round 6
// 247.989 us; speedup vs baseline: 1.1603x; 1.0455x over previous
//
#include <hip/hip_runtime.h>
#include <cstdint>

#define BB 8192
#define TT 50
#define FF 24
#define ROWS 32
#define LOG2E 1.4426950408889634f

typedef __attribute__((ext_vector_type(8))) short short8;
typedef __attribute__((ext_vector_type(4))) float f32x4;

// sigmoid on pre-scaled input (weights carry log2e): 1/(1+2^-x), raw v_rcp
__device__ __forceinline__ float sig2(float xs){
  return __builtin_amdgcn_rcpf(1.0f + exp2f(-xs));
}

// 2-way bf16 split (truncation) -- weights only
__device__ __forceinline__ void split2(float w, unsigned short& s1, unsigned short& s2){
  unsigned b = __float_as_uint(w);
  s1 = (unsigned short)(b >> 16);
  float r = w - __uint_as_float(b & 0xFFFF0000u);
  s2 = (unsigned short)(__float_as_uint(r) >> 16);
}

// single bf16 RNE
__device__ __forceinline__ unsigned short rne16(float v){
  unsigned b = __float_as_uint(v);
  b += 0x7FFFu + ((b >> 16) & 1u);
  return (unsigned short)(b >> 16);
}

// two bf16 RNE packed into one dword (lo=a, hi=b)
__device__ __forceinline__ unsigned pack2(float a, float b){
  unsigned ua = __float_as_uint(a); ua += 0x7FFFu + ((ua >> 16) & 1u);
  unsigned ub = __float_as_uint(b); ub += 0x7FFFu + ((ub >> 16) & 1u);
  return (ua >> 16) | (ub & 0xFFFF0000u);
}

#define MFMA(A,B,C) __builtin_amdgcn_mfma_f32_16x16x32_bf16((A),(B),(C),0,0,0)

// Round 14: R13 skeleton with four changes:
//  1. sigmoid = rcpf(1+exp2(-z')): plain -O3 compiled 1/(1+exp(-x)) as a
//     correctly-rounded fdiv (~10 inst, extra trans) -- the missing VALU.
//  2. i,f,o weight rows & biases pre-scaled by log2e at pack time (g/relu
//     rows unscaled) -> no per-sigmoid v_mul.
//  3. hidden-unit map u = 8*w7 + 2*quad + tp: the per-wave tile pair's h
//     values are ADJACENT -> one packed-bf16 b32 LDS write (B-frag reads
//     are by k index -- unaffected by who writes where).
//  4. ae_A + ae_C fused: h2 handoff is block-local via a2[1] (written in
//     the t=TT phase exactly like a normal step -> race-free); L3/dense
//     weights loaded AFTER loop-A (register liveness). Kills the
//     inter-kernel gap + h2ws round trip.
// zcol map per 16-wide tile: zc = (m&3)*<4H/4> + u(tile, m>>2); lane
// (quad,li) C reg i2 = gate i2 (i,f,g,o) of unit u(tile,quad), row li.

__global__ __launch_bounds__(1024,4) void ae_fused(
    const float* __restrict__ x,
    const float* __restrict__ W1, const float* __restrict__ U1, const float* __restrict__ b1,
    const float* __restrict__ W2, const float* __restrict__ U2, const float* __restrict__ b2,
    const float* __restrict__ W3, const float* __restrict__ U3, const float* __restrict__ b3,
    const float* __restrict__ Wd, const float* __restrict__ bd,
    float* __restrict__ out)
{
  constexpr int AS1 = 104, AS2 = 40, AS3 = 72;
  __shared__ __align__(16) unsigned short a1[2][ROWS*AS1]; // [slot][row*AS1 + (x24|h1 64|pad)]
  __shared__ __align__(16) unsigned short a2[2][ROWS*AS2]; // [slot][row*AS2 + h2(32)|pad]
  __shared__ __align__(16) unsigned short a3[2][ROWS*AS3]; // [slot][row*AS3 + h3(64)|pad]

  const int tid = threadIdx.x, wave = tid>>6, lane = tid&63;
  const int quad = lane>>4, li = lane&15;
  const int w7 = wave&7, rg = wave>>3;
  const int b0 = blockIdx.x*ROWS;
  const int arow = rg*16 + li;

  const int gl = li & 3;                       // gate row this lane packs
  const float scl = (gl==2) ? 1.0f : LOG2E;    // g(relu) unscaled

  // ---- L1 weight A-frags (2-split, scaled): u = 8*w7 + 2*(m>>2) + tp ----
  short8 A1w[2][3], A2w[2][3];
  f32x4 bi1[2];
#pragma unroll
  for (int tp=0; tp<2; ++tp){
    const int zc = gl*64 + 8*w7 + 2*(li>>2) + tp;
#pragma unroll
    for (int ks=0; ks<3; ++ks){
      short8 v1, v2;
#pragma unroll
      for (int j=0; j<8; ++j){
        const int k = ks*32 + quad*8 + j;
        float w = (k<24) ? W1[k*256+zc] : ((k<88) ? U1[(k-24)*256+zc] : 0.f);
        unsigned short s1,s2; split2(w*scl,s1,s2);
        v1[j]=(short)s1; v2[j]=(short)s2;
      }
      A1w[tp][ks]=v1; A2w[tp][ks]=v2;
    }
#pragma unroll
    for (int i2=0;i2<4;++i2)
      bi1[tp][i2] = b1[i2*64 + 8*w7 + 2*quad + tp] * ((i2==2)?1.0f:LOG2E);
  }
  // ---- L2 weight A-frags: u2 = 4*w7 + (m>>2) ----
  short8 A1w2[3], A2w2[3];
  f32x4 bi2;
  {
    const int zc = gl*32 + 4*w7 + (li>>2);
#pragma unroll
    for (int ks=0; ks<3; ++ks){
      short8 v1, v2;
#pragma unroll
      for (int j=0; j<8; ++j){
        const int k = ks*32 + quad*8 + j;
        float w = (k<64) ? W2[k*128+zc] : U2[(k-64)*128+zc];
        unsigned short s1,s2; split2(w*scl,s1,s2);
        v1[j]=(short)s1; v2[j]=(short)s2;
      }
      A1w2[ks]=v1; A2w2[ks]=v2;
    }
#pragma unroll
    for (int i2=0;i2<4;++i2)
      bi2[i2] = b2[i2*32 + 4*w7 + quad] * ((i2==2)?1.0f:LOG2E);
  }

  // zero LDS (h regions read 0 at t=0; pads stay 0; a3 for loop-C)
  { unsigned* p1 = (unsigned*)a1; for (int i=tid;i<2*ROWS*AS1/2;i+=1024) p1[i]=0u;
    unsigned* p2 = (unsigned*)a2; for (int i=tid;i<2*ROWS*AS2/2;i+=1024) p2[i]=0u;
    unsigned* p3 = (unsigned*)a3; for (int i=tid;i<2*ROWS*AS3/2;i+=1024) p3[i]=0u; }
  __syncthreads();
  // stage x(0) into slot 0
  if (tid < ROWS*FF){
    const int r = tid/FF, f = tid - r*FF;
    a1[0][r*AS1+f] = rne16(x[((size_t)(b0+r)*TT + 0)*FF + f]);
  }
  // x prefetch (threads tid<768): va=x(t+1), vb=x(t+2)
  int pr=0, pf=0; const float* xp=nullptr;
  float va=0.f, vb=0.f;
  const bool st = (tid < ROWS*FF);
  if (st){
    pr = tid/FF; pf = tid - pr*FF;
    xp = x + (size_t)(b0+pr)*TT*FF + pf;
    va = xp[1*FF];
    vb = xp[2*FF];
  }
  float c1s[2] = {0.f,0.f};
  float c2s = 0.f;
  const int rb1 = arow*AS1;
  const int rb2 = arow*AS2;
  const int hw1p = rb1 + 24 + 8*w7 + 2*quad;   // pair write (tp=0,1 adjacent)
  const int hw2 = rb2 + 4*w7 + quad;
  __syncthreads();

  // =================== loop A: L1 + L2 ===================
#pragma unroll 1
  for (int t=0; t<=TT; ++t){
    const int s = t&1, ns = s^1;
    float vc = 0.f;
    if (st && t+3 < TT) vc = xp[(t+3)*FF];
    // ---- L1: z1(t) + gates -> h1(t) ----
    if (t < TT){
      short8 Ba[3];
#pragma unroll
      for (int ks=0; ks<3; ++ks)
        Ba[ks] = *(const short8*)&a1[s][rb1 + ks*32 + quad*8];
      float hp[2];
#pragma unroll
      for (int tp=0; tp<2; ++tp){
        f32x4 C = bi1[tp];
#pragma unroll
        for (int ks=0; ks<3; ++ks){
          C = MFMA(A1w[tp][ks], Ba[ks], C);
          C = MFMA(A2w[tp][ks], Ba[ks], C);
        }
        const float ig = sig2(C[0]), fg = sig2(C[1]);
        const float gg = fmaxf(C[2],0.f), og = sig2(C[3]);
        const float cn = fg*c1s[tp] + ig*gg; c1s[tp] = cn;
        hp[tp] = og*fmaxf(cn,0.f);
      }
      *(unsigned*)&a1[ns][hw1p] = pack2(hp[0], hp[1]);
    }
    // ---- L2: z2(t-1) + gates -> h2(t-1) ----
    if (t >= 1){
      f32x4 C = bi2;
#pragma unroll
      for (int ks=0; ks<2; ++ks){
        short8 Ba = *(const short8*)&a1[s][rb1 + 24 + ks*32 + quad*8];
        C = MFMA(A1w2[ks], Ba, C);
        C = MFMA(A2w2[ks], Ba, C);
      }
      {
        short8 Ba = *(const short8*)&a2[s][rb2 + quad*8];
        C = MFMA(A1w2[2], Ba, C);
        C = MFMA(A2w2[2], Ba, C);
      }
      const float ig = sig2(C[0]), fg = sig2(C[1]);
      const float gg = fmaxf(C[2],0.f), og = sig2(C[3]);
      const float cn = fg*c2s + ig*gg; c2s = cn;
      const float h = og*fmaxf(cn,0.f);
      a2[ns][hw2] = rne16(h);   // at t==TT this lands in a2[1] = final h2
    }
    // ---- x staging ----
    if (st && t < TT-1){
      a1[ns][pr*AS1+pf] = rne16(va);
      va = vb; vb = vc;
    }
    __syncthreads();
  }

  // =================== prologue C: L3 + dense weights ===================
  short8 A1u[2][2], A2u[2][2];
  short8 A1w3[2], A2w3[2];
  f32x4 bi3[2];
#pragma unroll
  for (int tp=0; tp<2; ++tp){
    const int zc = gl*64 + 8*w7 + 2*(li>>2) + tp;
#pragma unroll
    for (int ks=0; ks<2; ++ks){
      short8 v1, v2;
#pragma unroll
      for (int j=0; j<8; ++j){
        const int k = ks*32 + quad*8 + j;
        float w = U3[k*256+zc];
        unsigned short s1,s2; split2(w*scl,s1,s2);
        v1[j]=(short)s1; v2[j]=(short)s2;
      }
      A1u[tp][ks]=v1; A2u[tp][ks]=v2;
    }
    {
      short8 v1, v2;
#pragma unroll
      for (int j=0; j<8; ++j){
        const int k = quad*8 + j;
        float w = W3[k*256+zc];
        unsigned short s1,s2; split2(w*scl,s1,s2);
        v1[j]=(short)s1; v2[j]=(short)s2;
      }
      A1w3[tp]=v1; A2w3[tp]=v2;
    }
#pragma unroll
    for (int i2=0;i2<4;++i2)
      bi3[tp][i2] = b3[i2*64 + 8*w7 + 2*quad + tp] * ((i2==2)?1.0f:LOG2E);
  }
  const bool dW = (w7 < 2);
  const int dcol = w7*16 + li;
  const bool dOK = dW && (dcol < 24);
  const float bdv = dOK ? bd[dcol] : 0.f;
  short8 Bd1[2], Bd2[2];
  if (dW){
#pragma unroll
    for (int ks=0; ks<2; ++ks){
      short8 v1, v2;
#pragma unroll
      for (int j=0; j<8; ++j){
        const int k = ks*32 + quad*8 + j;
        float w = dOK ? Wd[k*24+dcol] : 0.f;
        unsigned short s1,s2; split2(w,s1,s2);
        v1[j]=(short)s1; v2[j]=(short)s2;
      }
      Bd1[ks]=v1; Bd2[ks]=v2;
    }
  }

  // ZR = b3 + h2@W3 (h2 bf16 in a2[1], written by loop-A's t=TT phase)
  f32x4 zr[2];
  {
    short8 Ba = *(const short8*)&a2[1][rb2 + quad*8];
#pragma unroll
    for (int tp=0; tp<2; ++tp){
      f32x4 C = bi3[tp];
      C = MFMA(A1w3[tp], Ba, C);
      C = MFMA(A2w3[tp], Ba, C);
      zr[tp] = C;
    }
  }
  float c3s[2] = {0.f,0.f};
  const int rb3 = arow*AS3;
  const int hw3p = rb3 + 8*w7 + 2*quad;       // pair write

  // =================== loop C: L3 + fused dense ===================
#pragma unroll 1
  for (int t=0; t<=TT; ++t){
    const int s = t&1, ns = s^1;
    if (t < TT){
      short8 Ba[2];
#pragma unroll
      for (int ks=0; ks<2; ++ks)
        Ba[ks] = *(const short8*)&a3[s][rb3 + ks*32 + quad*8];
      float hp[2];
#pragma unroll
      for (int tp=0; tp<2; ++tp){
        f32x4 C = zr[tp];
#pragma unroll
        for (int ks=0; ks<2; ++ks){
          C = MFMA(A1u[tp][ks], Ba[ks], C);
          C = MFMA(A2u[tp][ks], Ba[ks], C);
        }
        const float ig = sig2(C[0]), fg = sig2(C[1]);
        const float gg = fmaxf(C[2],0.f), og = sig2(C[3]);
        const float cn = fg*c3s[tp] + ig*gg; c3s[tp] = cn;
        hp[tp] = og*fmaxf(cn,0.f);
      }
      *(unsigned*)&a3[ns][hw3p] = pack2(hp[0], hp[1]);
      // dense on h3(t-1) (same Ba frags), out column t-1
      if (dW && t > 0){
        f32x4 Cd = {bdv,bdv,bdv,bdv};
#pragma unroll
        for (int ks=0; ks<2; ++ks){
          Cd = MFMA(Ba[ks], Bd1[ks], Cd);
          Cd = MFMA(Ba[ks], Bd2[ks], Cd);
        }
        if (dcol < 24){
#pragma unroll
          for (int i2=0;i2<4;++i2)
            out[((size_t)(b0+rg*16+quad*4+i2)*TT + (t-1))*FF + dcol] = Cd[i2];
        }
      }
    } else {
      // t == TT: final dense on h3(TT-1)
      if (dW){
        f32x4 Cd = {bdv,bdv,bdv,bdv};
#pragma unroll
        for (int ks=0; ks<2; ++ks){
          short8 Ba = *(const short8*)&a3[s][rb3 + ks*32 + quad*8];
          Cd = MFMA(Ba, Bd1[ks], Cd);
          Cd = MFMA(Ba, Bd2[ks], Cd);
        }
        if (dcol < 24){
#pragma unroll
          for (int i2=0;i2<4;++i2)
            out[((size_t)(b0+rg*16+quad*4+i2)*TT + (TT-1))*FF + dcol] = Cd[i2];
        }
      }
    }
    __syncthreads();
  }
}

extern "C" void kernel_launch(void* const* d_in, const int* in_sizes, int n_in,
                              void* d_out, int out_size, void* d_ws, size_t ws_size,
                              hipStream_t stream){
  const float* x  = (const float*)d_in[0];
  const float* W1 = (const float*)d_in[1];
  const float* U1 = (const float*)d_in[2];
  const float* b1 = (const float*)d_in[3];
  const float* W2 = (const float*)d_in[4];
  const float* U2 = (const float*)d_in[5];
  const float* b2 = (const float*)d_in[6];
  const float* W3 = (const float*)d_in[7];
  const float* U3 = (const float*)d_in[8];
  const float* b3 = (const float*)d_in[9];
  const float* Wd = (const float*)d_in[10];
  const float* bd = (const float*)d_in[11];
  float* out = (float*)d_out;

  hipLaunchKernelGGL(ae_fused, dim3(BB/ROWS), dim3(1024), 0, stream,
                     x, W1, U1, b1, W2, U2, b2, W3, U3, b3, Wd, bd, out);
}